// Round 8
// baseline (424.400 us; speedup 1.0000x reference)
//
#include <hip/hip_runtime.h>
#include <math.h>

// Problem constants: 20 qubits, B=16 batch, RX chain on qubit 0,
// 2-qubit Hamiltonian evolution on qubits (2,5), observable = sum_q Z_q.
// State layout: (dim, B) row-major => flat idx = i*B + b; qubit q bit of i is at
// bit position (19 - q). So qubit 0 -> bit 19, qubit 2 -> bit 17, qubit 5 -> bit 14.
constexpr int NQ     = 20;
constexpr int DIM    = 1 << NQ;
constexpr int B      = 16;
constexpr int GROUPS = 1 << 17;       // DIM / 8 (octets over bits 19,17,14)
constexpr int GPB    = 32;            // groups per tile (one LDS tile = 32 KB)
constexpr int TILES  = GROUPS / GPB;  // 4096
constexpr int NBLK   = 1024;
constexpr int TPB    = TILES / NBLK;  // 4 consecutive tiles per block
constexpr int NTHR   = 512;

// ws layout: [0 .. NBLK*16) per-block partials (floats); at byte NBLK*64: counter.
// Rounds 0-7 accounting: each kernel boundary costs ~17us in this harness
// (r2: 2 kernels=159.2 w/ fused 48; r7: 3 kernels=177.7 w/ fused 46+reduce 3).
// So: merge prep + fused + reduce into ONE kernel. Prep is computed per-block
// into LDS (redundant but concurrent; U never touches global). Final reduce via
// threadfence + atomic-counter last-block pattern (device-scope per G16);
// counter zeroed by a stream-ordered 4-byte memset each launch (graph-safe).
__global__ __launch_bounds__(NTHR, 2) void mega_kernel(
    const float* __restrict__ sre, const float* __restrict__ sim,
    const float* __restrict__ hre, const float* __restrict__ him,
    const float* __restrict__ theta, const float* __restrict__ tv,
    float* __restrict__ partial, unsigned* __restrict__ cnt,
    float* __restrict__ out) {
  // pool: phase A = six fp64 [16][16] matrices; phase B = st[16*512] floats.
  __shared__ double pool[4096];            // 32 KB
  __shared__ __align__(16) float u_f[16 * 36];  // padded stride 36: 2-way max on b128
  __shared__ float cs_lds[32];
  __shared__ float red[16];
  __shared__ double nrm[16][4];
  __shared__ int    scl[16];
  __shared__ int    scmax_s;
  __shared__ int    lastflag;

  float*  st  = (float*)pool;
  double* Mre = pool;          // [16][16] flattened
  double* Mim = pool + 256;
  double* Ar  = pool + 512;
  double* Ai  = pool + 768;
  double* Br  = pool + 1024;
  double* Bi  = pool + 1280;

  int t = threadIdx.x;
  if (t == 0) { scmax_s = 0; lastflag = 0; }
  if (t < 16) red[t] = 0.f;
  __syncthreads();

  // ================= Phase A: per-block prep (verbatim r2 math) =================
  {
    int pb = (t >> 4) & 15, e = t & 15, i = e >> 2, j = e & 3;
    bool act = (t < 256);

    if (act && e == 0) {
      double th = 0.0;
      for (int k = 0; k < 8; k++) th += (double)theta[k * B + pb];
      th *= 0.5;
      cs_lds[pb]      = (float)cos(th);
      cs_lds[16 + pb] = (float)sin(th);
    }
    if (act) {
      double tt  = (double)tv[pb];
      double are = hre[(i*4+j)*B + pb], aim = him[(i*4+j)*B + pb];
      double cre = hre[(j*4+i)*B + pb], cim = him[(j*4+i)*B + pb];
      double Hre = 0.5*(are + cre), Him = 0.5*(aim - cim);
      Mre[pb*16 + e] = tt * Him;     // M = -i t H
      Mim[pb*16 + e] = -tt * Hre;
    }
    __syncthreads();
    if (act && j == 0) {
      double r = 0.0;
      for (int m = 0; m < 4; m++) r += fabs(Mre[pb*16 + i*4+m]) + fabs(Mim[pb*16 + i*4+m]);
      nrm[pb][i] = r;
    }
    __syncthreads();
    if (act && e == 0) {
      double ninf = fmax(fmax(nrm[pb][0], nrm[pb][1]), fmax(nrm[pb][2], nrm[pb][3]));
      int sc = 0;
      while (ninf > 0.25 && sc < 40) { ninf *= 0.5; sc++; }
      scl[pb] = sc;
      atomicMax(&scmax_s, sc);
    }
    __syncthreads();
    int scmax = scmax_s;
    int sc = act ? scl[pb] : 0;
    if (act) {
      double scale = ldexp(1.0, -sc);
      Mre[pb*16+e] *= scale; Mim[pb*16+e] *= scale;
      Ar[pb*16+e] = (i == j) ? 1.0 : 0.0;   // T = I
      Ai[pb*16+e] = 0.0;
    }
    __syncthreads();

    double *Tr = Ar, *Ti = Ai, *Pr = Br, *Pi = Bi;
    // Taylor via Horner: for k=13..1: T = I + M*T/k
    for (int k = 13; k >= 1; k--) {
      if (act) {
        double rr = 0.0, ii = 0.0;
        for (int m = 0; m < 4; m++) {
          double mr = Mre[pb*16 + i*4+m], mi = Mim[pb*16 + i*4+m];
          double xr = Tr[pb*16 + m*4+j], xi = Ti[pb*16 + m*4+j];
          rr += mr*xr - mi*xi;
          ii += mr*xi + mi*xr;
        }
        double inv = 1.0 / (double)k;
        Pr[pb*16+e] = rr*inv + ((i == j) ? 1.0 : 0.0);
        Pi[pb*16+e] = ii*inv;
      }
      { double* s0 = Tr; Tr = Pr; Pr = s0; s0 = Ti; Ti = Pi; Pi = s0; }
      __syncthreads();
    }
    // Squaring (uniform scmax iterations; q >= sc copies forward)
    for (int q = 0; q < scmax; q++) {
      if (act) {
        double rr, ii;
        if (q < sc) {
          rr = 0.0; ii = 0.0;
          for (int m = 0; m < 4; m++) {
            double xr = Tr[pb*16 + i*4+m], xi = Ti[pb*16 + i*4+m];
            double yr = Tr[pb*16 + m*4+j], yi = Ti[pb*16 + m*4+j];
            rr += xr*yr - xi*yi;
            ii += xr*yi + xi*yr;
          }
        } else { rr = Tr[pb*16+e]; ii = Ti[pb*16+e]; }
        Pr[pb*16+e] = rr; Pi[pb*16+e] = ii;
      }
      { double* s0 = Tr; Tr = Pr; Pr = s0; s0 = Ti; Ti = Pi; Pi = s0; }
      __syncthreads();
    }
    if (act) {
      u_f[pb*36 + e*2]     = (float)Tr[pb*16+e];
      u_f[pb*36 + e*2 + 1] = (float)Ti[pb*16+e];
    }
    __syncthreads();   // u_f/cs_lds ready; pool free for phase-B staging
  }

  // ================= Phase B: r7-verified async-staged tile loop =================
  int bb = t & 15;
  int gl = t >> 4;
  float c = cs_lds[bb], s = cs_lds[16 + bb];
  float ur[4][4], ui[4][4];
  {
    const float* ue = u_f + bb * 36;
    #pragma unroll
    for (int i2 = 0; i2 < 4; i2++) {
      float4 p0 = *(const float4*)(ue + i2 * 8);      // ur0,ui0,ur1,ui1
      float4 p1 = *(const float4*)(ue + i2 * 8 + 4);  // ur2,ui2,ur3,ui3
      ur[i2][0] = p0.x; ui[i2][0] = p0.y; ur[i2][1] = p0.z; ui[i2][1] = p0.w;
      ur[i2][2] = p1.x; ui[i2][2] = p1.y; ur[i2][3] = p1.z; ui[i2][3] = p1.w;
    }
  }

  int l  = t & 63;
  int wv = t >> 6;
  float acc = 0.f;

  for (int tt2 = 0; tt2 < TPB; tt2++) {
    int g0 = (blockIdx.x * TPB + tt2) * GPB;   // 32-aligned => low 5 bits zero
    int base0 = (g0 & 0x3FFF) | ((g0 & 0xC000) << 1) | ((g0 & 0x10000) << 2);

    // Stage 32 KB via async global->LDS: 4 x 1KB per wave, no VGPR round-trip.
    #pragma unroll
    for (int p = 0; p < 4; p++) {
      int cb    = p * 512 + wv * 64;   // wave-uniform 16B-chunk base
      int panel = cb >> 7;
      int wofs  = (cb & 127) << 2;
      int jj    = panel >> 1;
      const float* src = (panel & 1) ? sim : sre;
      int off = (((jj >> 2) & 1) << 19) | (((jj >> 1) & 1) << 17) | ((jj & 1) << 14);
      const float* gsrc = src + (size_t)(base0 + off) * 16 + wofs + l * 4; // 16B/lane
      float* ldst = &st[panel * 512 + wofs];   // wave-uniform; HW adds lane*16B
      __builtin_amdgcn_global_load_lds(
          (const __attribute__((address_space(1))) void*)gsrc,
          (__attribute__((address_space(3))) void*)ldst,
          16, 0, 0);
    }
    __syncthreads();   // vmcnt(0) drained before barrier: tile visible

    // State for this (group, batch): conflict-free scalar LDS reads
    float ar[8], ai[8];
    #pragma unroll
    for (int j = 0; j < 8; j++) {
      ar[j] = st[(2 * j) * 512 + t];
      ai[j] = st[(2 * j + 1) * 512 + t];
    }

    // RX(theta_sum) on qubit 0 (bit j>>2): pairs (j, j+4)
    #pragma unroll
    for (int j = 0; j < 4; j++) {
      float xr = ar[j], xi = ai[j], yr = ar[j+4], yi = ai[j+4];
      ar[j]   = c*xr + s*yi;   ai[j]   = c*xi - s*yr;
      ar[j+4] = s*xi + c*yr;   ai[j+4] = c*yi - s*xr;
    }

    // Ue on (qubit2,qubit5) + weight-folded |amp|^2 (verified body)
    int base = base0 + gl;
    int pc = __popc(base);
    float wb = (float)(17 - 2*pc);
    #pragma unroll
    for (int h = 0; h < 2; h++) {
      float w0 = wb + (h ? -1.f : 1.f);
      #pragma unroll
      for (int k = 0; k < 4; k++) {
        float rr = 0.f, ii = 0.f;
        #pragma unroll
        for (int m = 0; m < 4; m++) {
          float xr = ar[h*4+m], xi = ai[h*4+m];
          rr = fmaf(ur[k][m], xr, rr); rr = fmaf(-ui[k][m], xi, rr);
          ii = fmaf(ur[k][m], xi, ii); ii = fmaf(ui[k][m], xr, ii);
        }
        int sb = ((k>>1)&1) + (k&1);
        float w = w0 + (float)(2 - 2*sb);
        acc = fmaf(rr*rr + ii*ii, w, acc);
      }
    }
    __syncthreads();   // tile consumed before next staging overwrites st
  }

  // ================= Phase C: block partial + last-block final reduce =============
  acc += __shfl_xor(acc, 16, 64);
  acc += __shfl_xor(acc, 32, 64);
  if ((t & 63) < 16) atomicAdd(&red[t & 15], acc);
  __syncthreads();
  if (t < 16) partial[blockIdx.x * 16 + t] = red[t];
  __threadfence();                 // device-scope release of partial stores
  __syncthreads();
  if (t == 0) {
    unsigned old = atomicAdd(cnt, 1u);
    lastflag = (old == (unsigned)(NBLK - 1));
  }
  __syncthreads();                 // lastflag block-uniform => barriers below legal
  if (lastflag) {
    __threadfence();               // acquire side: see all blocks' partials
    float a2 = 0.f;
    for (int r = t >> 4; r < NBLK; r += 32)
      a2 += partial[r * 16 + (t & 15)];         // coalesced: t maps flat
    a2 += __shfl_xor(a2, 16, 64);
    a2 += __shfl_xor(a2, 32, 64);
    if (t < 16) red[t] = 0.f;
    __syncthreads();
    if ((t & 63) < 16) atomicAdd(&red[t & 15], a2);
    __syncthreads();
    if (t < 16) out[t] = red[t];
  }
}

extern "C" void kernel_launch(void* const* d_in, const int* in_sizes, int n_in,
                              void* d_out, int out_size, void* d_ws, size_t ws_size,
                              hipStream_t stream) {
  const float* sre = (const float*)d_in[0];
  const float* sim = (const float*)d_in[1];
  const float* hre = (const float*)d_in[2];
  const float* him = (const float*)d_in[3];
  const float* th  = (const float*)d_in[4];
  const float* tv  = (const float*)d_in[5];

  float* ws = (float*)d_ws;
  float* partial = ws;                                   // NBLK*16 floats
  unsigned* cnt = (unsigned*)((char*)d_ws + NBLK * 16 * sizeof(float));

  // Stream-ordered 4-byte zero of the arrival counter (graph-capture-safe:
  // the harness itself enqueues hipMemsetAsync on this stream).
  hipMemsetAsync((void*)cnt, 0, sizeof(unsigned), stream);
  mega_kernel<<<NBLK, NTHR, 0, stream>>>(sre, sim, hre, him, th, tv,
                                         partial, cnt, (float*)d_out);
}